// Round 1
// baseline (297.542 us; speedup 1.0000x reference)
//
#include <hip/hip_runtime.h>
#include <stdint.h>

// ---------------- problem constants ----------------
#define T_STEPS 2048
#define BATCH   32
#define NIN     512            // K
#define NOUT    256
#define MROWS   (T_STEPS*BATCH)   // 65536
#define NTOT    (4*NOUT)          // 1024 gemm columns (Wx|Wf|Wr|Wc)
#define BO      (BATCH*NOUT)      // 8192 recurrence lanes
#define NCHUNK  32
#define CHLEN   (T_STEPS/NCHUNK)  // 64

typedef _Float16 f16x8 __attribute__((ext_vector_type(8)));
typedef _Float16 f16x4 __attribute__((ext_vector_type(4)));
typedef float    fx4   __attribute__((ext_vector_type(4)));

// ---------------- weight conversion: 4x [256,512] f32 -> Wcat [1024][512] f16 ----
__global__ __launch_bounds__(256) void convert_w(
    const float* __restrict__ Wx, const float* __restrict__ Wf,
    const float* __restrict__ Wr, const float* __restrict__ Wc,
    _Float16* __restrict__ Wcat)
{
    int idx = blockIdx.x * 256 + threadIdx.x;   // 131072 threads, 4 elems each
    int n  = idx >> 7;            // 128 float4-chunks per 512-wide row
    int k4 = (idx & 127) * 4;
    int g = n >> 8, o = n & 255;
    const float* W = (g == 0) ? Wx : (g == 1) ? Wf : (g == 2) ? Wr : Wc;
    float4 v = *(const float4*)(W + o * NIN + k4);
    f16x4 h;
    h[0] = (_Float16)v.x; h[1] = (_Float16)v.y;
    h[2] = (_Float16)v.z; h[3] = (_Float16)v.w;
    *(f16x4*)(Wcat + n * NIN + k4) = h;
}

// ---------------- fused projection GEMM ----------------
// out[m][n] = dot(xt[m][0:512], Wcat[n][0:512]);  n-group g=n>>8 selects
// {xp, sigmoid(+bf), sigmoid(+br), +bc} -> four f16 arrays [MROWS][256].
#define BM 128
#define BN 128
#define BK 64

__global__ __launch_bounds__(256) void gemm_proj(
    const float*    __restrict__ xt,      // [MROWS][512] f32
    const _Float16* __restrict__ Wcat,    // [1024][512]  f16
    const float* __restrict__ bfv, const float* __restrict__ brv, const float* __restrict__ bcv,
    _Float16* __restrict__ xp_h, _Float16* __restrict__ f_h,
    _Float16* __restrict__ r_h,  _Float16* __restrict__ cx_h)
{
    __shared__ _Float16 As[BM * BK];   // 16 KB, XOR-swizzled rows of 128 B
    __shared__ _Float16 Bs[BN * BK];   // 16 KB
    char* AsB = (char*)As;
    char* BsB = (char*)Bs;

    const int tid  = threadIdx.x;
    const int lane = tid & 63;
    const int wave = tid >> 6;
    const int wr = wave >> 1, wc = wave & 1;     // 2x2 waves, 64x64 each
    const int lr = lane & 15, lk = lane >> 4;
    const long m0 = (long)blockIdx.x * BM;

    for (int bni = 0; bni < 2; ++bni) {
        const int bn = blockIdx.y * 2 + bni;     // 0..7
        const int n0 = bn * BN;

        fx4 acc[4][4];
        #pragma unroll
        for (int i = 0; i < 4; ++i)
            #pragma unroll
            for (int j = 0; j < 4; ++j) acc[i][j] = (fx4){0.f, 0.f, 0.f, 0.f};

        for (int kb = 0; kb < NIN; kb += BK) {
            __syncthreads();
            // stage A: 128x64 f32 -> f16 (1024 chunks of 8 elems, 4/thread)
            #pragma unroll
            for (int it = 0; it < 4; ++it) {
                int c = tid + it * 256;
                int row = c >> 3, ck = c & 7;
                const float* src = xt + (m0 + row) * NIN + kb + ck * 8;
                float4 v0 = *(const float4*)src;
                float4 v1 = *(const float4*)(src + 4);
                f16x8 h;
                h[0] = (_Float16)v0.x; h[1] = (_Float16)v0.y;
                h[2] = (_Float16)v0.z; h[3] = (_Float16)v0.w;
                h[4] = (_Float16)v1.x; h[5] = (_Float16)v1.y;
                h[6] = (_Float16)v1.z; h[7] = (_Float16)v1.w;
                int byte = row * 128 + ((ck * 16) ^ ((row & 7) << 4));
                *(f16x8*)(AsB + byte) = h;
            }
            // stage B: 128x64 f16 (already converted)
            #pragma unroll
            for (int it = 0; it < 4; ++it) {
                int c = tid + it * 256;
                int row = c >> 3, ck = c & 7;
                f16x8 h = *(const f16x8*)(Wcat + (long)(n0 + row) * NIN + kb + ck * 8);
                int byte = row * 128 + ((ck * 16) ^ ((row & 7) << 4));
                *(f16x8*)(BsB + byte) = h;
            }
            __syncthreads();
            // compute: 2 k-halves x 16 MFMA
            #pragma unroll
            for (int kk = 0; kk < 2; ++kk) {
                f16x8 af[4], bg[4];
                const int kbyte = (kk * 32 + lk * 8) * 2;
                #pragma unroll
                for (int mf = 0; mf < 4; ++mf) {
                    int row = wr * 64 + mf * 16 + lr;
                    af[mf] = *(const f16x8*)(AsB + row * 128 + (kbyte ^ ((row & 7) << 4)));
                }
                #pragma unroll
                for (int nf = 0; nf < 4; ++nf) {
                    int row = wc * 64 + nf * 16 + lr;
                    bg[nf] = *(const f16x8*)(BsB + row * 128 + (kbyte ^ ((row & 7) << 4)));
                }
                #pragma unroll
                for (int mf = 0; mf < 4; ++mf)
                    #pragma unroll
                    for (int nf = 0; nf < 4; ++nf)
                        acc[mf][nf] = __builtin_amdgcn_mfma_f32_16x16x32_f16(
                            af[mf], bg[nf], acc[mf][nf], 0, 0, 0);
            }
        }

        // epilogue: C/D layout col=lane&15, row=(lane>>4)*4+reg  [verified m89]
        const int g = n0 >> 8;   // uniform per (block, bni)
        _Float16* outp = (g == 0) ? xp_h : (g == 1) ? f_h : (g == 2) ? r_h : cx_h;
        #pragma unroll
        for (int mf = 0; mf < 4; ++mf) {
            #pragma unroll
            for (int nf = 0; nf < 4; ++nf) {
                int colg = n0 + wc * 64 + nf * 16 + lr;
                int o = colg & 255;
                #pragma unroll
                for (int j = 0; j < 4; ++j) {
                    long row = m0 + wr * 64 + mf * 16 + lk * 4 + j;
                    float v = acc[mf][nf][j];
                    _Float16 hv;
                    if (g == 0) {
                        hv = (_Float16)v;
                    } else if (g == 3) {
                        hv = (_Float16)(v + bcv[o]);
                    } else {
                        float pre = v + ((g == 1) ? bfv[o] : brv[o]);
                        float e = __expf(-pre);
                        hv = (_Float16)(__builtin_amdgcn_rcpf(1.0f + e));
                    }
                    outp[row * NOUT + o] = hv;
                }
            }
        }
    }
}

// ---------------- pass 2a: per-chunk affine composition -------------
// c_out = A*c_in + B with A = prod(f), B = recurrence from c=0
__global__ __launch_bounds__(256) void chunk_scan_a(
    const _Float16* __restrict__ f_h, const _Float16* __restrict__ xp_h,
    float* __restrict__ chunkA, float* __restrict__ chunkB)
{
    int tid = blockIdx.x * 256 + threadIdx.x;   // 262144
    int chunk = tid >> 13;
    int bo = tid & (BO - 1);
    long base = (long)chunk * CHLEN * BO + bo;
    float a = 1.f, cc = 0.f;
    #pragma unroll 4
    for (int s = 0; s < CHLEN; ++s) {
        long i = base + (long)s * BO;
        float fv = (float)f_h[i];
        float xv = (float)xp_h[i];
        cc = fv * cc + (1.f - fv) * xv;
        a *= fv;
    }
    chunkA[tid] = a;
    chunkB[tid] = cc;
}

// ---------------- pass 2b: propagate chunk states (tiny, sequential) ----
__global__ __launch_bounds__(256) void chunk_prop(
    const float* __restrict__ ct0,
    const float* __restrict__ chunkA, const float* __restrict__ chunkB,
    float* __restrict__ cin, float* __restrict__ c_final)
{
    int bo = blockIdx.x * 256 + threadIdx.x;   // 8192
    float c = ct0[bo];
    #pragma unroll
    for (int ch = 0; ch < NCHUNK; ++ch) {
        cin[ch * BO + bo] = c;
        c = chunkA[ch * BO + bo] * c + chunkB[ch * BO + bo];
    }
    c_final[bo] = c;
}

// ---------------- pass 2c: final scan producing ht -------------------
__global__ __launch_bounds__(256) void chunk_scan_h(
    const _Float16* __restrict__ xp_h, const _Float16* __restrict__ f_h,
    const _Float16* __restrict__ r_h,  const _Float16* __restrict__ cx_h,
    const float* __restrict__ cin, float* __restrict__ ht)
{
    int tid = blockIdx.x * 256 + threadIdx.x;   // 262144
    int chunk = tid >> 13;
    int bo = tid & (BO - 1);
    long base = (long)chunk * CHLEN * BO + bo;
    float c = cin[tid];
    #pragma unroll 4
    for (int s = 0; s < CHLEN; ++s) {
        long i = base + (long)s * BO;
        float fv = (float)f_h[i];
        float xv = (float)xp_h[i];
        float rv = (float)r_h[i];
        float cxv = (float)cx_h[i];
        c = fv * c + (1.f - fv) * xv;
        float e = __expf(2.f * c);                       // tanh = (e-1)/(e+1)
        float th = (e - 1.f) * __builtin_amdgcn_rcpf(e + 1.f);
        ht[i] = rv * th + (1.f - rv) * cxv;
    }
}

// ---------------- launcher ----------------
extern "C" void kernel_launch(void* const* d_in, const int* in_sizes, int n_in,
                              void* d_out, int out_size, void* d_ws, size_t ws_size,
                              hipStream_t stream) {
    const float* xt  = (const float*)d_in[0];
    const float* ct0 = (const float*)d_in[1];
    const float* Wx  = (const float*)d_in[2];
    const float* Wf  = (const float*)d_in[3];
    const float* bf_ = (const float*)d_in[4];
    const float* Wr  = (const float*)d_in[5];
    const float* br_ = (const float*)d_in[6];
    const float* Wc  = (const float*)d_in[7];
    const float* bc_ = (const float*)d_in[8];

    float* ht      = (float*)d_out;
    float* c_final = ht + (size_t)MROWS * NOUT;    // 16777216

    char* ws = (char*)d_ws;
    _Float16* Wcat = (_Float16*)ws;                         // 1 MiB
    _Float16* xp_h = (_Float16*)(ws + (1 << 20));           // 32 MiB each
    _Float16* f_h  = xp_h + (size_t)MROWS * NOUT;
    _Float16* r_h  = f_h  + (size_t)MROWS * NOUT;
    _Float16* cx_h = r_h  + (size_t)MROWS * NOUT;
    float* chunkA  = (float*)(cx_h + (size_t)MROWS * NOUT); // 1 MiB
    float* chunkB  = chunkA + NCHUNK * BO;                  // 1 MiB
    float* cin     = chunkB + NCHUNK * BO;                  // 1 MiB
    // total ws use: 1 + 128 + 3 = 132 MiB

    convert_w<<<512, 256, 0, stream>>>(Wx, Wf, Wr, Wc, Wcat);
    gemm_proj<<<dim3(MROWS / BM, 4), 256, 0, stream>>>(
        xt, Wcat, bf_, br_, bc_, xp_h, f_h, r_h, cx_h);
    chunk_scan_a<<<(NCHUNK * BO) / 256, 256, 0, stream>>>(f_h, xp_h, chunkA, chunkB);
    chunk_prop<<<BO / 256, 256, 0, stream>>>(ct0, chunkA, chunkB, cin, c_final);
    chunk_scan_h<<<(NCHUNK * BO) / 256, 256, 0, stream>>>(xp_h, f_h, r_h, cx_h, cin, ht);
}

// Round 2
// 206.040 us; speedup vs baseline: 1.4441x; 1.4441x over previous
//
#include <hip/hip_runtime.h>
#include <stdint.h>

// ---------------- problem constants ----------------
#define T_STEPS 2048
#define BATCH   32
#define NIN     512
#define NOUT    256
#define MROWS   (T_STEPS*BATCH)   // 65536
#define BO      (BATCH*NOUT)      // 8192
#define NCHUNK  32
#define CHLEN   (T_STEPS/NCHUNK)  // 64

typedef _Float16 f16x8 __attribute__((ext_vector_type(8)));
typedef _Float16 f16x4 __attribute__((ext_vector_type(4)));
typedef float    fx4   __attribute__((ext_vector_type(4)));

#define LDSP(p) ((__attribute__((address_space(3))) void*)(p))
#define GLBP(p) ((const __attribute__((address_space(1))) void*)(p))

// ---------------- xt f32 -> f16 (one pass, dedups conversion) -------------
__global__ __launch_bounds__(256) void convert_x(
    const float* __restrict__ xt, _Float16* __restrict__ xh)
{
    long i = ((long)blockIdx.x * 256 + threadIdx.x) * 8;
    float4 v0 = *(const float4*)(xt + i);
    float4 v1 = *(const float4*)(xt + i + 4);
    f16x8 h;
    h[0] = (_Float16)v0.x; h[1] = (_Float16)v0.y;
    h[2] = (_Float16)v0.z; h[3] = (_Float16)v0.w;
    h[4] = (_Float16)v1.x; h[5] = (_Float16)v1.y;
    h[6] = (_Float16)v1.z; h[7] = (_Float16)v1.w;
    *(f16x8*)(xh + i) = h;
}

// ---------------- weights: 4x [256,512] f32 -> Wcat [1024][512] f16 -------
__global__ __launch_bounds__(256) void convert_w(
    const float* __restrict__ Wx, const float* __restrict__ Wf,
    const float* __restrict__ Wr, const float* __restrict__ Wc,
    _Float16* __restrict__ Wcat)
{
    int idx = blockIdx.x * 256 + threadIdx.x;
    int n  = idx >> 7;
    int k4 = (idx & 127) * 4;
    int g = n >> 8, o = n & 255;
    const float* W = (g == 0) ? Wx : (g == 1) ? Wf : (g == 2) ? Wr : Wc;
    float4 v = *(const float4*)(W + o * NIN + k4);
    f16x4 h;
    h[0] = (_Float16)v.x; h[1] = (_Float16)v.y;
    h[2] = (_Float16)v.z; h[3] = (_Float16)v.w;
    *(f16x4*)(Wcat + n * NIN + k4) = h;
}

// ---------------- fused projection GEMM (m97 structure) ----------------
// 128x128 tile, BK=64, global_load_lds(16B) with pre-swizzled source so
// LDS holds the XOR-swizzled layout: elem (row, colbyte) at row*128 +
// (colbyte ^ ((row&7)<<4)).
#define BM 128
#define BN 128
#define BK 64

__global__ __launch_bounds__(256) void gemm_proj(
    const _Float16* __restrict__ xh,      // [MROWS][512] f16
    const _Float16* __restrict__ Wcat,    // [1024][512]  f16
    const float* __restrict__ bfv, const float* __restrict__ brv, const float* __restrict__ bcv,
    _Float16* __restrict__ xp_h, _Float16* __restrict__ f_h,
    _Float16* __restrict__ r_h,  _Float16* __restrict__ cx_h)
{
    __shared__ _Float16 As[BM * BK];   // 16 KB
    __shared__ _Float16 Bs[BN * BK];   // 16 KB
    char* AsB = (char*)As;
    char* BsB = (char*)Bs;

    const int tid  = threadIdx.x;
    const int lane = tid & 63;
    const int w    = tid >> 6;
    const int wr = w >> 1, wc = w & 1;       // 2x2 waves, 64x64 each
    const int lr = lane & 15, lk = lane >> 4;

    // bijective XCD swizzle: 4096 wgs, 512 per XCD; consecutive wgids within
    // an XCD share A-slabs (colgroup fast) -> A stays in that XCD's L2.
    int wg = (blockIdx.x & 7) * 512 + (blockIdx.x >> 3);
    const int  rowblk = wg >> 3;             // 0..511
    const int  cg     = wg & 7;              // column group 0..7
    const long m0 = (long)rowblk * BM;
    const int  n0 = cg * BN;

    // ---- staging source addresses (pre-swizzled global) ----
    // chunk ci = w*4+it covers LDS bytes [ci*1024, ci*1024+1024), lane l at +l*16.
    // LDS byte L=ci*1024+l*16 -> row=ci*8+(l>>3), stored col = (l&7)*16,
    // logical col = stored ^ ((row&7)<<4), row&7 == l>>3.
    const int src_cl = (((lane & 7) ^ (lane >> 3)) << 4);
    const char* gA = (const char*)xh +
        (m0 + w * 32 + (lane >> 3)) * (NIN * 2) + src_cl;
    const char* gB = (const char*)Wcat +
        ((long)n0 + w * 32 + (lane >> 3)) * (NIN * 2) + src_cl;
    char* ldsA = AsB + w * 4096;
    char* ldsB = BsB + w * 4096;

    fx4 acc[4][4];
    #pragma unroll
    for (int i = 0; i < 4; ++i)
        #pragma unroll
        for (int j = 0; j < 4; ++j) acc[i][j] = (fx4){0.f, 0.f, 0.f, 0.f};

    for (int kb = 0; kb < NIN / BK; ++kb) {
        // stage A+B tiles: 8 x global_load_lds(16B) per thread
        #pragma unroll
        for (int it = 0; it < 4; ++it)
            __builtin_amdgcn_global_load_lds(GLBP(gA + it * (8 * NIN * 2) + kb * (BK * 2)),
                                             LDSP(ldsA + it * 1024), 16, 0, 0);
        #pragma unroll
        for (int it = 0; it < 4; ++it)
            __builtin_amdgcn_global_load_lds(GLBP(gB + it * (8 * NIN * 2) + kb * (BK * 2)),
                                             LDSP(ldsB + it * 1024), 16, 0, 0);
        __syncthreads();   // drains vmcnt+lgkmcnt

        #pragma unroll
        for (int kk = 0; kk < 2; ++kk) {
            f16x8 af[4], bg[4];
            const int kbyte = kk * 64 + lk * 16;
            #pragma unroll
            for (int mf = 0; mf < 4; ++mf) {
                int row = wr * 64 + mf * 16 + lr;
                af[mf] = *(const f16x8*)(AsB + row * 128 + (kbyte ^ ((row & 7) << 4)));
            }
            #pragma unroll
            for (int nf = 0; nf < 4; ++nf) {
                int row = wc * 64 + nf * 16 + lr;
                bg[nf] = *(const f16x8*)(BsB + row * 128 + (kbyte ^ ((row & 7) << 4)));
            }
            #pragma unroll
            for (int mf = 0; mf < 4; ++mf)
                #pragma unroll
                for (int nf = 0; nf < 4; ++nf)
                    acc[mf][nf] = __builtin_amdgcn_mfma_f32_16x16x32_f16(
                        af[mf], bg[nf], acc[mf][nf], 0, 0, 0);
        }
        __syncthreads();   // compute done before restage
    }

    // epilogue: C/D layout col=lane&15, row=(lane>>4)*4+reg [verified m89]
    const int g = cg >> 1;
    const int obase = (cg & 1) * 128;
    _Float16* outp = (g == 0) ? xp_h : (g == 1) ? f_h : (g == 2) ? r_h : cx_h;
    const float* bias = (g == 1) ? bfv : (g == 2) ? brv : (g == 3) ? bcv : nullptr;
    #pragma unroll
    for (int mf = 0; mf < 4; ++mf) {
        #pragma unroll
        for (int nf = 0; nf < 4; ++nf) {
            int o = obase + wc * 64 + nf * 16 + lr;
            float bv = (g == 0) ? 0.f : bias[o];
            #pragma unroll
            for (int j = 0; j < 4; ++j) {
                long row = m0 + wr * 64 + mf * 16 + lk * 4 + j;
                float v = acc[mf][nf][j] + bv;
                _Float16 hv;
                if (g == 1 || g == 2) {
                    float e = __expf(-v);
                    hv = (_Float16)(__builtin_amdgcn_rcpf(1.0f + e));
                } else {
                    hv = (_Float16)v;
                }
                outp[row * NOUT + o] = hv;
            }
        }
    }
}

// ---------------- pass 2a: per-chunk affine composition -------------
__global__ __launch_bounds__(256) void chunk_scan_a(
    const _Float16* __restrict__ f_h, const _Float16* __restrict__ xp_h,
    float* __restrict__ chunkA, float* __restrict__ chunkB)
{
    int tid = blockIdx.x * 256 + threadIdx.x;   // 262144
    int chunk = tid >> 13;
    int bo = tid & (BO - 1);
    long base = (long)chunk * CHLEN * BO + bo;
    float a = 1.f, cc = 0.f;
    #pragma unroll 4
    for (int s = 0; s < CHLEN; ++s) {
        long i = base + (long)s * BO;
        float fv = (float)f_h[i];
        float xv = (float)xp_h[i];
        cc = fv * cc + (1.f - fv) * xv;
        a *= fv;
    }
    chunkA[tid] = a;
    chunkB[tid] = cc;
}

// ---------------- pass 2b: propagate chunk states ----
__global__ __launch_bounds__(256) void chunk_prop(
    const float* __restrict__ ct0,
    const float* __restrict__ chunkA, const float* __restrict__ chunkB,
    float* __restrict__ cin, float* __restrict__ c_final)
{
    int bo = blockIdx.x * 256 + threadIdx.x;   // 8192
    float c = ct0[bo];
    #pragma unroll
    for (int ch = 0; ch < NCHUNK; ++ch) {
        cin[ch * BO + bo] = c;
        c = chunkA[ch * BO + bo] * c + chunkB[ch * BO + bo];
    }
    c_final[bo] = c;
}

// ---------------- pass 2c: final scan producing ht -------------------
__global__ __launch_bounds__(256) void chunk_scan_h(
    const _Float16* __restrict__ xp_h, const _Float16* __restrict__ f_h,
    const _Float16* __restrict__ r_h,  const _Float16* __restrict__ cx_h,
    const float* __restrict__ cin, float* __restrict__ ht)
{
    int tid = blockIdx.x * 256 + threadIdx.x;   // 262144
    int chunk = tid >> 13;
    int bo = tid & (BO - 1);
    long base = (long)chunk * CHLEN * BO + bo;
    float c = cin[tid];
    #pragma unroll 4
    for (int s = 0; s < CHLEN; ++s) {
        long i = base + (long)s * BO;
        float fv = (float)f_h[i];
        float xv = (float)xp_h[i];
        float rv = (float)r_h[i];
        float cxv = (float)cx_h[i];
        c = fv * c + (1.f - fv) * xv;
        float e = __expf(2.f * c);                       // tanh = (e-1)/(e+1)
        float th = (e - 1.f) * __builtin_amdgcn_rcpf(e + 1.f);
        ht[i] = rv * th + (1.f - rv) * cxv;
    }
}

// ---------------- launcher ----------------
extern "C" void kernel_launch(void* const* d_in, const int* in_sizes, int n_in,
                              void* d_out, int out_size, void* d_ws, size_t ws_size,
                              hipStream_t stream) {
    const float* xt  = (const float*)d_in[0];
    const float* ct0 = (const float*)d_in[1];
    const float* Wx  = (const float*)d_in[2];
    const float* Wf  = (const float*)d_in[3];
    const float* bf_ = (const float*)d_in[4];
    const float* Wr  = (const float*)d_in[5];
    const float* br_ = (const float*)d_in[6];
    const float* Wc  = (const float*)d_in[7];
    const float* bc_ = (const float*)d_in[8];

    float* ht      = (float*)d_out;
    float* c_final = ht + (size_t)MROWS * NOUT;

    char* ws = (char*)d_ws;
    _Float16* Wcat = (_Float16*)ws;                          // 1 MiB
    _Float16* xh   = (_Float16*)(ws + (1 << 20));            // 64 MiB
    _Float16* xp_h = xh + (size_t)MROWS * NIN;               // 32 MiB each
    _Float16* f_h  = xp_h + (size_t)MROWS * NOUT;
    _Float16* r_h  = f_h  + (size_t)MROWS * NOUT;
    _Float16* cx_h = r_h  + (size_t)MROWS * NOUT;
    float* chunkA  = (float*)(cx_h + (size_t)MROWS * NOUT);  // 1 MiB
    float* chunkB  = chunkA + NCHUNK * BO;
    float* cin     = chunkB + NCHUNK * BO;
    // total ws use ~ 196 MiB

    convert_w<<<512, 256, 0, stream>>>(Wx, Wf, Wr, Wc, Wcat);
    convert_x<<<(MROWS * NIN / 8) / 256, 256, 0, stream>>>(xt, xh);
    gemm_proj<<<(MROWS / BM) * 8, 256, 0, stream>>>(
        xh, Wcat, bf_, br_, bc_, xp_h, f_h, r_h, cx_h);
    chunk_scan_a<<<(NCHUNK * BO) / 256, 256, 0, stream>>>(f_h, xp_h, chunkA, chunkB);
    chunk_prop<<<BO / 256, 256, 0, stream>>>(ct0, chunkA, chunkB, cin, c_final);
    chunk_scan_h<<<(NCHUNK * BO) / 256, 256, 0, stream>>>(xp_h, f_h, r_h, cx_h, cin, ht);
}

// Round 3
// 194.461 us; speedup vs baseline: 1.5301x; 1.0595x over previous
//
#include <hip/hip_runtime.h>
#include <stdint.h>

// ---------------- problem constants ----------------
#define T_STEPS 2048
#define BATCH   32
#define NIN     512
#define NOUT    256
#define MROWS   (T_STEPS*BATCH)   // 65536
#define BO      (BATCH*NOUT)      // 8192
#define NCHUNK  32
#define CHLEN   (T_STEPS/NCHUNK)  // 64

typedef _Float16 f16x8 __attribute__((ext_vector_type(8)));
typedef _Float16 f16x4 __attribute__((ext_vector_type(4)));
typedef float    fx4   __attribute__((ext_vector_type(4)));

#define LDSP(p) ((__attribute__((address_space(3))) void*)(p))
#define GLBP(p) ((const __attribute__((address_space(1))) void*)(p))

#define BAR()       asm volatile("s_barrier" ::: "memory")
#define WAITLGKM0() do { asm volatile("s_waitcnt lgkmcnt(0)" ::: "memory"); __builtin_amdgcn_sched_barrier(0); } while(0)
#define WAITVM(n)   do { asm volatile("s_waitcnt vmcnt(" #n ")" ::: "memory"); __builtin_amdgcn_sched_barrier(0); } while(0)

// ---------------- xt f32 -> f16 ----------------
__global__ __launch_bounds__(256) void convert_x(
    const float* __restrict__ xt, _Float16* __restrict__ xh)
{
    long i = ((long)blockIdx.x * 256 + threadIdx.x) * 8;
    float4 v0 = *(const float4*)(xt + i);
    float4 v1 = *(const float4*)(xt + i + 4);
    f16x8 h;
    h[0] = (_Float16)v0.x; h[1] = (_Float16)v0.y;
    h[2] = (_Float16)v0.z; h[3] = (_Float16)v0.w;
    h[4] = (_Float16)v1.x; h[5] = (_Float16)v1.y;
    h[6] = (_Float16)v1.z; h[7] = (_Float16)v1.w;
    *(f16x8*)(xh + i) = h;
}

// ---------------- weights: 4x [256,512] f32 -> Wcat [1024][512] f16 -------
__global__ __launch_bounds__(256) void convert_w(
    const float* __restrict__ Wx, const float* __restrict__ Wf,
    const float* __restrict__ Wr, const float* __restrict__ Wc,
    _Float16* __restrict__ Wcat)
{
    int idx = blockIdx.x * 256 + threadIdx.x;
    int n  = idx >> 7;
    int k4 = (idx & 127) * 4;
    int g = n >> 8, o = n & 255;
    const float* W = (g == 0) ? Wx : (g == 1) ? Wf : (g == 2) ? Wr : Wc;
    float4 v = *(const float4*)(W + o * NIN + k4);
    f16x4 h;
    h[0] = (_Float16)v.x; h[1] = (_Float16)v.y;
    h[2] = (_Float16)v.z; h[3] = (_Float16)v.w;
    *(f16x4*)(Wcat + n * NIN + k4) = h;
}

// ---------------- 256x256 8-phase GEMM (T3+T4+T5 structure) ----------------
#define BM 256
#define BN 256
#define BK 64
#define NKT (NIN / BK)   // 8 K-tiles

__global__ __launch_bounds__(512) void gemm_proj(
    const _Float16* __restrict__ xh,      // [MROWS][512] f16
    const _Float16* __restrict__ Wcat,    // [1024][512]  f16
    const float* __restrict__ bfv, const float* __restrict__ brv, const float* __restrict__ bcv,
    _Float16* __restrict__ xp_h, _Float16* __restrict__ f_h,
    _Float16* __restrict__ r_h,  _Float16* __restrict__ cx_h)
{
    __shared__ char lds[131072];   // A: [c][h] at c*32768+h*16384 ; B: +65536

    const int tid  = threadIdx.x;
    const int lane = tid & 63;
    const int w    = tid >> 6;       // 0..7
    const int wrq  = w >> 2;         // 0..1
    const int wcq  = w & 3;          // 0..3
    const int lr = lane & 15, lk = lane >> 4;

    // bijective XCD swizzle: 1024 wgs, 128/XCD, colgroup fast within XCD
    int wg = (blockIdx.x & 7) * 128 + (blockIdx.x >> 3);
    const int  rowblk = wg >> 2;     // 0..255
    const int  cg     = wg & 3;      // 0..3  == output group
    const long m0 = (long)rowblk * BM;
    const int  n0 = cg * BN;

    const int rl8  = lane >> 3;
    const int scol = (((lane & 7) ^ rl8) << 4);
    const char* baseA = (const char*)xh   + (m0 + w * 8 + rl8) * 1024 + scol;
    const char* baseB = (const char*)Wcat + ((long)(n0 + w * 8 + rl8)) * 1024 + scol;

#define STAGE_A(t, h) do {                                                   \
        char* _d = lds + ((t) & 1) * 32768 + (h) * 16384 + w * 1024;         \
        const char* _s = baseA + (long)(h) * 131072 + (t) * 128;             \
        __builtin_amdgcn_global_load_lds(GLBP(_s),         LDSP(_d),        16, 0, 0); \
        __builtin_amdgcn_global_load_lds(GLBP(_s + 65536), LDSP(_d + 8192), 16, 0, 0); \
    } while (0)
#define STAGE_B(t, h) do {                                                   \
        char* _d = lds + 65536 + ((t) & 1) * 32768 + (h) * 16384 + w * 1024; \
        const char* _s = baseB + (long)(h) * 131072 + (t) * 128;             \
        __builtin_amdgcn_global_load_lds(GLBP(_s),         LDSP(_d),        16, 0, 0); \
        __builtin_amdgcn_global_load_lds(GLBP(_s + 65536), LDSP(_d + 8192), 16, 0, 0); \
    } while (0)

    fx4 acc[2][2][4][2];
    #pragma unroll
    for (int a = 0; a < 2; ++a)
        #pragma unroll
        for (int b = 0; b < 2; ++b)
            #pragma unroll
            for (int c = 0; c < 4; ++c)
                #pragma unroll
                for (int d = 0; d < 2; ++d)
                    acc[a][b][c][d] = (fx4){0.f, 0.f, 0.f, 0.f};

    f16x8 Ar[4][2];    // current A-half fragments [mf][kk]
    f16x8 B0r[2][2];   // B-half0 fragments [nf][kk]
    f16x8 B1r[2][2];   // B-half1 fragments

#define READ_A(c2, h) do {                                                   \
        _Pragma("unroll")                                                    \
        for (int mf = 0; mf < 4; ++mf) {                                     \
            int rl = wrq * 64 + mf * 16 + lr;                                \
            int rb = (c2) * 32768 + (h) * 16384 + rl * 128;                  \
            _Pragma("unroll")                                                \
            for (int kk = 0; kk < 2; ++kk)                                   \
                Ar[mf][kk] = *(const f16x8*)(lds + rb +                      \
                    ((kk * 64 + lk * 16) ^ ((rl & 7) << 4)));                \
        }                                                                    \
    } while (0)
#define READ_B(c2, h, dst) do {                                              \
        _Pragma("unroll")                                                    \
        for (int nf = 0; nf < 2; ++nf) {                                     \
            int rl = wcq * 32 + nf * 16 + lr;                                \
            int rb = 65536 + (c2) * 32768 + (h) * 16384 + rl * 128;          \
            _Pragma("unroll")                                                \
            for (int kk = 0; kk < 2; ++kk)                                   \
                dst[nf][kk] = *(const f16x8*)(lds + rb +                     \
                    ((kk * 64 + lk * 16) ^ ((rl & 7) << 4)));                \
        }                                                                    \
    } while (0)
#define MMACC(Qr, Qc, Br) do {                                               \
        __builtin_amdgcn_s_setprio(1);                                       \
        _Pragma("unroll")                                                    \
        for (int kk = 0; kk < 2; ++kk)                                       \
            _Pragma("unroll")                                                \
            for (int mf = 0; mf < 4; ++mf)                                   \
                _Pragma("unroll")                                            \
                for (int nf = 0; nf < 2; ++nf)                               \
                    acc[Qr][Qc][mf][nf] = __builtin_amdgcn_mfma_f32_16x16x32_f16( \
                        Ar[mf][kk], Br[nf][kk], acc[Qr][Qc][mf][nf], 0, 0, 0);    \
        __builtin_amdgcn_s_setprio(0);                                       \
    } while (0)

    // ---- prologue: tile0 all 4 halves + tile1 A0,B0; land tile0 ----
    STAGE_A(0, 0); STAGE_B(0, 0); STAGE_B(0, 1); STAGE_A(0, 1);
    STAGE_A(1, 0); STAGE_B(1, 0);
    WAITVM(4);
    BAR();

    for (int t = 0; t < NKT; ++t) {
        const int c2 = t & 1;
        // ---- phase 1: Q(0,0) ----
        READ_A(c2, 0);
        READ_B(c2, 0, B0r);
        if (t + 1 < NKT) STAGE_B(t + 1, 1);
        BAR();
        WAITLGKM0();
        MMACC(0, 0, B0r);
        BAR();
        // ---- phase 2: Q(0,1) ----
        READ_B(c2, 1, B1r);
        if (t + 1 < NKT) STAGE_A(t + 1, 1);
        BAR();
        WAITLGKM0();
        MMACC(0, 1, B1r);
        BAR();
        // ---- phase 3: Q(1,0) ----
        READ_A(c2, 1);
        if (t + 2 < NKT) STAGE_A(t + 2, 0);
        BAR();
        WAITLGKM0();
        MMACC(1, 0, B0r);
        BAR();
        // ---- phase 4: Q(1,1) ----
        if (t + 2 < NKT) STAGE_B(t + 2, 0);
        BAR();
        MMACC(1, 1, B1r);
        if (t < NKT - 2)       WAITVM(4);
        else if (t == NKT - 2) WAITVM(0);
        BAR();
    }

    // ---- epilogue ----
    const int g = cg;   // uniform per block
    _Float16* outp = (g == 0) ? xp_h : (g == 1) ? f_h : (g == 2) ? r_h : cx_h;
    const float* bias = (g == 1) ? bfv : (g == 2) ? brv : (g == 3) ? bcv : nullptr;
    #pragma unroll
    for (int Qr = 0; Qr < 2; ++Qr) {
        #pragma unroll
        for (int Qc = 0; Qc < 2; ++Qc) {
            #pragma unroll
            for (int mf = 0; mf < 4; ++mf) {
                #pragma unroll
                for (int nf = 0; nf < 2; ++nf) {
                    int o = Qc * 128 + wcq * 32 + nf * 16 + lr;
                    float bv = (g == 0) ? 0.f : bias[o];
                    #pragma unroll
                    for (int j = 0; j < 4; ++j) {
                        long row = m0 + Qr * 128 + wrq * 64 + mf * 16 + lk * 4 + j;
                        float v = acc[Qr][Qc][mf][nf][j] + bv;
                        _Float16 hv;
                        if (g == 1 || g == 2) {
                            float e = __expf(-v);
                            hv = (_Float16)(__builtin_amdgcn_rcpf(1.0f + e));
                        } else {
                            hv = (_Float16)v;
                        }
                        outp[row * NOUT + o] = hv;
                    }
                }
            }
        }
    }
}

// ---------------- pass 2a: per-chunk affine composition -------------
__global__ __launch_bounds__(256) void chunk_scan_a(
    const _Float16* __restrict__ f_h, const _Float16* __restrict__ xp_h,
    float* __restrict__ chunkA, float* __restrict__ chunkB)
{
    int tid = blockIdx.x * 256 + threadIdx.x;   // 262144
    int chunk = tid >> 13;
    int bo = tid & (BO - 1);
    long base = (long)chunk * CHLEN * BO + bo;
    float a = 1.f, cc = 0.f;
    #pragma unroll 4
    for (int s = 0; s < CHLEN; ++s) {
        long i = base + (long)s * BO;
        float fv = (float)f_h[i];
        float xv = (float)xp_h[i];
        cc = fv * cc + (1.f - fv) * xv;
        a *= fv;
    }
    chunkA[tid] = a;
    chunkB[tid] = cc;
}

// ---------------- pass 2b: propagate chunk states ----
__global__ __launch_bounds__(256) void chunk_prop(
    const float* __restrict__ ct0,
    const float* __restrict__ chunkA, const float* __restrict__ chunkB,
    float* __restrict__ cin, float* __restrict__ c_final)
{
    int bo = blockIdx.x * 256 + threadIdx.x;   // 8192
    float c = ct0[bo];
    #pragma unroll
    for (int ch = 0; ch < NCHUNK; ++ch) {
        cin[ch * BO + bo] = c;
        c = chunkA[ch * BO + bo] * c + chunkB[ch * BO + bo];
    }
    c_final[bo] = c;
}

// ---------------- pass 2c: final scan producing ht -------------------
__global__ __launch_bounds__(256) void chunk_scan_h(
    const _Float16* __restrict__ xp_h, const _Float16* __restrict__ f_h,
    const _Float16* __restrict__ r_h,  const _Float16* __restrict__ cx_h,
    const float* __restrict__ cin, float* __restrict__ ht)
{
    int tid = blockIdx.x * 256 + threadIdx.x;   // 262144
    int chunk = tid >> 13;
    int bo = tid & (BO - 1);
    long base = (long)chunk * CHLEN * BO + bo;
    float c = cin[tid];
    #pragma unroll 4
    for (int s = 0; s < CHLEN; ++s) {
        long i = base + (long)s * BO;
        float fv = (float)f_h[i];
        float xv = (float)xp_h[i];
        float rv = (float)r_h[i];
        float cxv = (float)cx_h[i];
        c = fv * c + (1.f - fv) * xv;
        float e = __expf(2.f * c);                       // tanh = (e-1)/(e+1)
        float th = (e - 1.f) * __builtin_amdgcn_rcpf(e + 1.f);
        ht[i] = rv * th + (1.f - rv) * cxv;
    }
}

// ---------------- launcher ----------------
extern "C" void kernel_launch(void* const* d_in, const int* in_sizes, int n_in,
                              void* d_out, int out_size, void* d_ws, size_t ws_size,
                              hipStream_t stream) {
    const float* xt  = (const float*)d_in[0];
    const float* ct0 = (const float*)d_in[1];
    const float* Wx  = (const float*)d_in[2];
    const float* Wf  = (const float*)d_in[3];
    const float* bf_ = (const float*)d_in[4];
    const float* Wr  = (const float*)d_in[5];
    const float* br_ = (const float*)d_in[6];
    const float* Wc  = (const float*)d_in[7];
    const float* bc_ = (const float*)d_in[8];

    float* ht      = (float*)d_out;
    float* c_final = ht + (size_t)MROWS * NOUT;

    char* ws = (char*)d_ws;
    _Float16* Wcat = (_Float16*)ws;                          // 1 MiB
    _Float16* xh   = (_Float16*)(ws + (1 << 20));            // 64 MiB
    _Float16* xp_h = xh + (size_t)MROWS * NIN;               // 32 MiB each
    _Float16* f_h  = xp_h + (size_t)MROWS * NOUT;
    _Float16* r_h  = f_h  + (size_t)MROWS * NOUT;
    _Float16* cx_h = r_h  + (size_t)MROWS * NOUT;
    float* chunkA  = (float*)(cx_h + (size_t)MROWS * NOUT);  // 1 MiB
    float* chunkB  = chunkA + NCHUNK * BO;
    float* cin     = chunkB + NCHUNK * BO;

    convert_w<<<512, 256, 0, stream>>>(Wx, Wf, Wr, Wc, Wcat);
    convert_x<<<(MROWS * NIN / 8) / 256, 256, 0, stream>>>(xt, xh);
    gemm_proj<<<(MROWS / BM) * 4, 512, 0, stream>>>(
        xh, Wcat, bf_, br_, bc_, xp_h, f_h, r_h, cx_h);
    chunk_scan_a<<<(NCHUNK * BO) / 256, 256, 0, stream>>>(f_h, xp_h, chunkA, chunkB);
    chunk_prop<<<BO / 256, 256, 0, stream>>>(ct0, chunkA, chunkB, cin, c_final);
    chunk_scan_h<<<(NCHUNK * BO) / 256, 256, 0, stream>>>(xp_h, f_h, r_h, cx_h, cin, ht);
}

// Round 4
// 192.931 us; speedup vs baseline: 1.5422x; 1.0079x over previous
//
#include <hip/hip_runtime.h>
#include <stdint.h>

// ---------------- problem constants ----------------
#define T_STEPS 2048
#define BATCH   32
#define NIN     512
#define NOUT    256
#define MROWS   (T_STEPS*BATCH)   // 65536
#define BO      (BATCH*NOUT)      // 8192
#define NCHUNK  32
#define CHLEN   (T_STEPS/NCHUNK)  // 64

typedef _Float16 f16x8 __attribute__((ext_vector_type(8)));
typedef _Float16 f16x4 __attribute__((ext_vector_type(4)));
typedef float    fx4   __attribute__((ext_vector_type(4)));

#define LDSP(p) ((__attribute__((address_space(3))) void*)(p))
#define GLBP(p) ((const __attribute__((address_space(1))) void*)(p))

#define BAR()       asm volatile("s_barrier" ::: "memory")
#define WAITLGKM0() do { asm volatile("s_waitcnt lgkmcnt(0)" ::: "memory"); __builtin_amdgcn_sched_barrier(0); } while(0)
#define WAITVM(n)   do { asm volatile("s_waitcnt vmcnt(" #n ")" ::: "memory"); __builtin_amdgcn_sched_barrier(0); } while(0)

// ---------------- xt f32 -> f16 ----------------
__global__ __launch_bounds__(256) void convert_x(
    const float* __restrict__ xt, _Float16* __restrict__ xh)
{
    long i = ((long)blockIdx.x * 256 + threadIdx.x) * 8;
    float4 v0 = *(const float4*)(xt + i);
    float4 v1 = *(const float4*)(xt + i + 4);
    f16x8 h;
    h[0] = (_Float16)v0.x; h[1] = (_Float16)v0.y;
    h[2] = (_Float16)v0.z; h[3] = (_Float16)v0.w;
    h[4] = (_Float16)v1.x; h[5] = (_Float16)v1.y;
    h[6] = (_Float16)v1.z; h[7] = (_Float16)v1.w;
    *(f16x8*)(xh + i) = h;
}

// ---------------- weights: 4x [256,512] f32 -> Wcat [1024][512] f16 -------
__global__ __launch_bounds__(256) void convert_w(
    const float* __restrict__ Wx, const float* __restrict__ Wf,
    const float* __restrict__ Wr, const float* __restrict__ Wc,
    _Float16* __restrict__ Wcat)
{
    int idx = blockIdx.x * 256 + threadIdx.x;
    int n  = idx >> 7;
    int k4 = (idx & 127) * 4;
    int g = n >> 8, o = n & 255;
    const float* W = (g == 0) ? Wx : (g == 1) ? Wf : (g == 2) ? Wr : Wc;
    float4 v = *(const float4*)(W + o * NIN + k4);
    f16x4 h;
    h[0] = (_Float16)v.x; h[1] = (_Float16)v.y;
    h[2] = (_Float16)v.z; h[3] = (_Float16)v.w;
    *(f16x4*)(Wcat + n * NIN + k4) = h;
}

// ---------------- persistent 256x256 4-phase GEMM ----------------
// Each block: fixed output group cg, sweeps 4 M-tiles (1024 rows) in one
// continuous 32-tile pipeline (global tile g = mt*8 + kt).  Swapped-operand
// MFMA (mfma(B,A)): D col(lane&15) -> m-row, reg j -> output column o, so
// epilogue stores packed f16x4 (8 B) per fragment.
#define BM 256
#define BN 256
#define BK 64
#define NGT 32            // 4 m-tiles x 8 k-tiles

__global__ __launch_bounds__(512) void gemm_proj(
    const _Float16* __restrict__ xh,      // [MROWS][512] f16
    const _Float16* __restrict__ Wcat,    // [1024][512]  f16
    const float* __restrict__ bfv, const float* __restrict__ brv, const float* __restrict__ bcv,
    _Float16* __restrict__ xp_h, _Float16* __restrict__ f_h,
    _Float16* __restrict__ r_h,  _Float16* __restrict__ cx_h)
{
    __shared__ char lds[131072];   // A: [c][h] at c*32768+h*16384 ; B: +65536

    const int tid  = threadIdx.x;
    const int lane = tid & 63;
    const int w    = tid >> 6;       // 0..7
    const int wrq  = w >> 2;         // 0..1
    const int wcq  = w & 3;          // 0..3
    const int lr = lane & 15, lk = lane >> 4;

    // XCD-chunked bijective swizzle: 256 wgs, 32/XCD; consecutive wg within
    // an XCD -> the 4 cg-blocks sharing A rows (same mgrp) are co-XCD.
    int wg = (blockIdx.x & 7) * 32 + (blockIdx.x >> 3);
    const int  cg   = wg & 3;        // output group 0..3
    const int  mgrp = wg >> 2;       // 0..63
    const long m0 = (long)mgrp * 1024;   // 4 m-tiles of 256 rows
    const int  n0 = cg * BN;

    const int rl8  = lane >> 3;
    const int scol = (((lane & 7) ^ rl8) << 4);
    const char* baseA = (const char*)xh   + (m0 + w * 8 + rl8) * 1024 + scol;
    const char* baseB = (const char*)Wcat + ((long)(n0 + w * 8 + rl8)) * 1024 + scol;

    // global tile g: mt=g>>3 (A row offset), kt=g&7 (K offset), parity g&1
#define STAGE_A(g, h) do {                                                   \
        char* _d = lds + ((g) & 1) * 32768 + (h) * 16384 + w * 1024;         \
        const char* _s = baseA + (long)((g) >> 3) * 262144                   \
                         + ((g) & 7) * 128 + (long)(h) * 131072;             \
        __builtin_amdgcn_global_load_lds(GLBP(_s),         LDSP(_d),        16, 0, 0); \
        __builtin_amdgcn_global_load_lds(GLBP(_s + 65536), LDSP(_d + 8192), 16, 0, 0); \
    } while (0)
#define STAGE_B(g, h) do {                                                   \
        char* _d = lds + 65536 + ((g) & 1) * 32768 + (h) * 16384 + w * 1024; \
        const char* _s = baseB + ((g) & 7) * 128 + (long)(h) * 131072;       \
        __builtin_amdgcn_global_load_lds(GLBP(_s),         LDSP(_d),        16, 0, 0); \
        __builtin_amdgcn_global_load_lds(GLBP(_s + 65536), LDSP(_d + 8192), 16, 0, 0); \
    } while (0)

    fx4 acc[2][2][4][2];
    #pragma unroll
    for (int a = 0; a < 2; ++a)
        #pragma unroll
        for (int b = 0; b < 2; ++b)
            #pragma unroll
            for (int c = 0; c < 4; ++c)
                #pragma unroll
                for (int d = 0; d < 2; ++d)
                    acc[a][b][c][d] = (fx4){0.f, 0.f, 0.f, 0.f};

    f16x8 Ar[4][2];    // current A-half fragments [mf][kk]
    f16x8 B0r[2][2];   // B-half0 fragments [nf][kk]
    f16x8 B1r[2][2];   // B-half1 fragments

#define READ_A(c2, h) do {                                                   \
        _Pragma("unroll")                                                    \
        for (int mf = 0; mf < 4; ++mf) {                                     \
            int rl = wrq * 64 + mf * 16 + lr;                                \
            int rb = (c2) * 32768 + (h) * 16384 + rl * 128;                  \
            _Pragma("unroll")                                                \
            for (int kk = 0; kk < 2; ++kk)                                   \
                Ar[mf][kk] = *(const f16x8*)(lds + rb +                      \
                    ((kk * 64 + lk * 16) ^ ((rl & 7) << 4)));                \
        }                                                                    \
    } while (0)
#define READ_B(c2, h, dst) do {                                              \
        _Pragma("unroll")                                                    \
        for (int nf = 0; nf < 2; ++nf) {                                     \
            int rl = wcq * 32 + nf * 16 + lr;                                \
            int rb = 65536 + (c2) * 32768 + (h) * 16384 + rl * 128;          \
            _Pragma("unroll")                                                \
            for (int kk = 0; kk < 2; ++kk)                                   \
                dst[nf][kk] = *(const f16x8*)(lds + rb +                     \
                    ((kk * 64 + lk * 16) ^ ((rl & 7) << 4)));                \
        }                                                                    \
    } while (0)
    // swapped operands: D[col=lane&15 -> m (A)], [reg j -> o (B)]
#define MMACC(Qr, Qc, Br) do {                                               \
        __builtin_amdgcn_s_setprio(1);                                       \
        _Pragma("unroll")                                                    \
        for (int kk = 0; kk < 2; ++kk)                                       \
            _Pragma("unroll")                                                \
            for (int mf = 0; mf < 4; ++mf)                                   \
                _Pragma("unroll")                                            \
                for (int nf = 0; nf < 2; ++nf)                               \
                    acc[Qr][Qc][mf][nf] = __builtin_amdgcn_mfma_f32_16x16x32_f16( \
                        Br[nf][kk], Ar[mf][kk], acc[Qr][Qc][mf][nf], 0, 0, 0);    \
        __builtin_amdgcn_s_setprio(0);                                       \
    } while (0)

    const int g_out = cg;
    _Float16* outp = (g_out == 0) ? xp_h : (g_out == 1) ? f_h : (g_out == 2) ? r_h : cx_h;
    const float* bias = (g_out == 1) ? bfv : (g_out == 2) ? brv : (g_out == 3) ? bcv : nullptr;

    // ---- prologue: tile0 all 4 halves + tile1 A0,B0; land tile0 ----
    STAGE_A(0, 0); STAGE_B(0, 0); STAGE_B(0, 1); STAGE_A(0, 1);
    STAGE_A(1, 0); STAGE_B(1, 0);
    WAITVM(4);
    BAR();

    for (int g = 0; g < NGT; ++g) {
        const int c2 = g & 1;
        // ---- phase 1: Q(0,0) ----
        READ_A(c2, 0);
        READ_B(c2, 0, B0r);
        if (g + 1 < NGT) STAGE_B(g + 1, 1);
        BAR();
        WAITLGKM0();
        MMACC(0, 0, B0r);
        BAR();
        // ---- phase 2: Q(0,1) ----
        READ_B(c2, 1, B1r);
        if (g + 1 < NGT) STAGE_A(g + 1, 1);
        BAR();
        WAITLGKM0();
        MMACC(0, 1, B1r);
        BAR();
        // ---- phase 3: Q(1,0) ----
        READ_A(c2, 1);
        if (g + 2 < NGT) STAGE_A(g + 2, 0);
        BAR();
        WAITLGKM0();
        MMACC(1, 0, B0r);
        BAR();
        // ---- phase 4: Q(1,1) ----
        if (g + 2 < NGT) STAGE_B(g + 2, 0);
        BAR();
        MMACC(1, 1, B1r);
        if (g < NGT - 2)       WAITVM(4);
        else if (g == NGT - 2) WAITVM(0);
        BAR();

        // ---- per-m-tile epilogue (g = mt*8+7): packed f16x4 stores ----
        if ((g & 7) == 7) {
            const long mbase = m0 + (long)(g >> 3) * 256;
            #pragma unroll
            for (int Qr = 0; Qr < 2; ++Qr) {
                #pragma unroll
                for (int Qc = 0; Qc < 2; ++Qc) {
                    #pragma unroll
                    for (int nf = 0; nf < 2; ++nf) {
                        const int ob = Qc * 128 + wcq * 32 + nf * 16 + lk * 4;
                        float4 bv4 = (g_out == 0) ? (float4){0.f, 0.f, 0.f, 0.f}
                                                  : *(const float4*)(bias + ob);
                        #pragma unroll
                        for (int mf = 0; mf < 4; ++mf) {
                            long row = mbase + Qr * 128 + wrq * 64 + mf * 16 + lr;
                            fx4 v = acc[Qr][Qc][mf][nf];
                            f16x4 hv;
                            if (g_out == 1 || g_out == 2) {
                                float p0 = v[0] + bv4.x, p1 = v[1] + bv4.y;
                                float p2 = v[2] + bv4.z, p3 = v[3] + bv4.w;
                                hv[0] = (_Float16)(__builtin_amdgcn_rcpf(1.0f + __expf(-p0)));
                                hv[1] = (_Float16)(__builtin_amdgcn_rcpf(1.0f + __expf(-p1)));
                                hv[2] = (_Float16)(__builtin_amdgcn_rcpf(1.0f + __expf(-p2)));
                                hv[3] = (_Float16)(__builtin_amdgcn_rcpf(1.0f + __expf(-p3)));
                            } else {
                                hv[0] = (_Float16)(v[0] + bv4.x);
                                hv[1] = (_Float16)(v[1] + bv4.y);
                                hv[2] = (_Float16)(v[2] + bv4.z);
                                hv[3] = (_Float16)(v[3] + bv4.w);
                            }
                            *(f16x4*)(outp + row * NOUT + ob) = hv;
                            acc[Qr][Qc][mf][nf] = (fx4){0.f, 0.f, 0.f, 0.f};
                        }
                    }
                }
            }
        }
    }
}

// ---------------- pass 2a: per-chunk affine composition -------------
__global__ __launch_bounds__(256) void chunk_scan_a(
    const _Float16* __restrict__ f_h, const _Float16* __restrict__ xp_h,
    float* __restrict__ chunkA, float* __restrict__ chunkB)
{
    int tid = blockIdx.x * 256 + threadIdx.x;   // 262144
    int chunk = tid >> 13;
    int bo = tid & (BO - 1);
    long base = (long)chunk * CHLEN * BO + bo;
    float a = 1.f, cc = 0.f;
    #pragma unroll 4
    for (int s = 0; s < CHLEN; ++s) {
        long i = base + (long)s * BO;
        float fv = (float)f_h[i];
        float xv = (float)xp_h[i];
        cc = fv * cc + (1.f - fv) * xv;
        a *= fv;
    }
    chunkA[tid] = a;
    chunkB[tid] = cc;
}

// ---------------- pass 2b: propagate chunk states ----
__global__ __launch_bounds__(256) void chunk_prop(
    const float* __restrict__ ct0,
    const float* __restrict__ chunkA, const float* __restrict__ chunkB,
    float* __restrict__ cin, float* __restrict__ c_final)
{
    int bo = blockIdx.x * 256 + threadIdx.x;   // 8192
    float c = ct0[bo];
    #pragma unroll
    for (int ch = 0; ch < NCHUNK; ++ch) {
        cin[ch * BO + bo] = c;
        c = chunkA[ch * BO + bo] * c + chunkB[ch * BO + bo];
    }
    c_final[bo] = c;
}

// ---------------- pass 2c: final scan producing ht -------------------
__global__ __launch_bounds__(256) void chunk_scan_h(
    const _Float16* __restrict__ xp_h, const _Float16* __restrict__ f_h,
    const _Float16* __restrict__ r_h,  const _Float16* __restrict__ cx_h,
    const float* __restrict__ cin, float* __restrict__ ht)
{
    int tid = blockIdx.x * 256 + threadIdx.x;   // 262144
    int chunk = tid >> 13;
    int bo = tid & (BO - 1);
    long base = (long)chunk * CHLEN * BO + bo;
    float c = cin[tid];
    #pragma unroll 4
    for (int s = 0; s < CHLEN; ++s) {
        long i = base + (long)s * BO;
        float fv = (float)f_h[i];
        float xv = (float)xp_h[i];
        float rv = (float)r_h[i];
        float cxv = (float)cx_h[i];
        c = fv * c + (1.f - fv) * xv;
        float e = __expf(2.f * c);                       // tanh = (e-1)/(e+1)
        float th = (e - 1.f) * __builtin_amdgcn_rcpf(e + 1.f);
        ht[i] = rv * th + (1.f - rv) * cxv;
    }
}

// ---------------- launcher ----------------
extern "C" void kernel_launch(void* const* d_in, const int* in_sizes, int n_in,
                              void* d_out, int out_size, void* d_ws, size_t ws_size,
                              hipStream_t stream) {
    const float* xt  = (const float*)d_in[0];
    const float* ct0 = (const float*)d_in[1];
    const float* Wx  = (const float*)d_in[2];
    const float* Wf  = (const float*)d_in[3];
    const float* bf_ = (const float*)d_in[4];
    const float* Wr  = (const float*)d_in[5];
    const float* br_ = (const float*)d_in[6];
    const float* Wc  = (const float*)d_in[7];
    const float* bc_ = (const float*)d_in[8];

    float* ht      = (float*)d_out;
    float* c_final = ht + (size_t)MROWS * NOUT;

    char* ws = (char*)d_ws;
    _Float16* Wcat = (_Float16*)ws;                          // 1 MiB
    _Float16* xh   = (_Float16*)(ws + (1 << 20));            // 64 MiB
    _Float16* xp_h = xh + (size_t)MROWS * NIN;               // 32 MiB each
    _Float16* f_h  = xp_h + (size_t)MROWS * NOUT;
    _Float16* r_h  = f_h  + (size_t)MROWS * NOUT;
    _Float16* cx_h = r_h  + (size_t)MROWS * NOUT;
    float* chunkA  = (float*)(cx_h + (size_t)MROWS * NOUT);  // 1 MiB
    float* chunkB  = chunkA + NCHUNK * BO;
    float* cin     = chunkB + NCHUNK * BO;

    convert_w<<<512, 256, 0, stream>>>(Wx, Wf, Wr, Wc, Wcat);
    convert_x<<<(MROWS * NIN / 8) / 256, 256, 0, stream>>>(xt, xh);
    gemm_proj<<<256, 512, 0, stream>>>(
        xh, Wcat, bf_, br_, bc_, xp_h, f_h, r_h, cx_h);
    chunk_scan_a<<<(NCHUNK * BO) / 256, 256, 0, stream>>>(f_h, xp_h, chunkA, chunkB);
    chunk_prop<<<BO / 256, 256, 0, stream>>>(ct0, chunkA, chunkB, cin, c_final);
    chunk_scan_h<<<(NCHUNK * BO) / 256, 256, 0, stream>>>(xp_h, f_h, r_h, cx_h, cin, ht);
}

// Round 5
// 188.857 us; speedup vs baseline: 1.5755x; 1.0216x over previous
//
#include <hip/hip_runtime.h>
#include <stdint.h>

// ---------------- problem constants ----------------
#define T_STEPS 2048
#define BATCH   32
#define NIN     512
#define NOUT    256
#define MROWS   (T_STEPS*BATCH)   // 65536
#define BO      (BATCH*NOUT)      // 8192
#define NCHUNK  32
#define CHLEN   (T_STEPS/NCHUNK)  // 64

typedef _Float16 f16x8 __attribute__((ext_vector_type(8)));
typedef _Float16 f16x4 __attribute__((ext_vector_type(4)));
typedef float    fx4   __attribute__((ext_vector_type(4)));

#define LDSP(p) ((__attribute__((address_space(3))) void*)(p))
#define GLBP(p) ((const __attribute__((address_space(1))) void*)(p))

#define BAR()       asm volatile("s_barrier" ::: "memory")
#define WAITLGKM0() do { asm volatile("s_waitcnt lgkmcnt(0)" ::: "memory"); __builtin_amdgcn_sched_barrier(0); } while(0)
#define WAITVM(n)   do { asm volatile("s_waitcnt vmcnt(" #n ")" ::: "memory"); __builtin_amdgcn_sched_barrier(0); } while(0)

// ---------------- xt f32 -> f16 ----------------
__global__ __launch_bounds__(256) void convert_x(
    const float* __restrict__ xt, _Float16* __restrict__ xh)
{
    long i = ((long)blockIdx.x * 256 + threadIdx.x) * 8;
    float4 v0 = *(const float4*)(xt + i);
    float4 v1 = *(const float4*)(xt + i + 4);
    f16x8 h;
    h[0] = (_Float16)v0.x; h[1] = (_Float16)v0.y;
    h[2] = (_Float16)v0.z; h[3] = (_Float16)v0.w;
    h[4] = (_Float16)v1.x; h[5] = (_Float16)v1.y;
    h[6] = (_Float16)v1.z; h[7] = (_Float16)v1.w;
    *(f16x8*)(xh + i) = h;
}

// ---------------- weights: 4x [256,512] f32 -> Wcat [1024][512] f16 -------
__global__ __launch_bounds__(256) void convert_w(
    const float* __restrict__ Wx, const float* __restrict__ Wf,
    const float* __restrict__ Wr, const float* __restrict__ Wc,
    _Float16* __restrict__ Wcat)
{
    int idx = blockIdx.x * 256 + threadIdx.x;
    int n  = idx >> 7;
    int k4 = (idx & 127) * 4;
    int g = n >> 8, o = n & 255;
    const float* W = (g == 0) ? Wx : (g == 1) ? Wf : (g == 2) ? Wr : Wc;
    float4 v = *(const float4*)(W + o * NIN + k4);
    f16x4 h;
    h[0] = (_Float16)v.x; h[1] = (_Float16)v.y;
    h[2] = (_Float16)v.z; h[3] = (_Float16)v.w;
    *(f16x4*)(Wcat + n * NIN + k4) = h;
}

// ---------------- persistent 256x256 GEMM, 2-barrier/K-step schedule ------
// Per K-step: 4 per-wave phases gated only by lgkmcnt; exactly TWO block
// barriers: (mid) between h0 ds_reads and h0 restages of the same parity,
// (end) after the per-wave vmcnt gate.  Waves free-run between barriers ->
// ds_read / MFMA / stage overlap across the 2 waves/SIMD (role-split).
#define BM 256
#define BN 256
#define BK 64
#define NGT 32            // 4 m-tiles x 8 k-tiles

__global__ __launch_bounds__(512) void gemm_proj(
    const _Float16* __restrict__ xh,      // [MROWS][512] f16
    const _Float16* __restrict__ Wcat,    // [1024][512]  f16
    const float* __restrict__ bfv, const float* __restrict__ brv, const float* __restrict__ bcv,
    _Float16* __restrict__ xp_h, _Float16* __restrict__ f_h,
    _Float16* __restrict__ r_h,  _Float16* __restrict__ cx_h)
{
    __shared__ char lds[131072];   // A: [c][h] at c*32768+h*16384 ; B: +65536

    const int tid  = threadIdx.x;
    const int lane = tid & 63;
    const int w    = tid >> 6;       // 0..7
    const int wrq  = w >> 2;         // 0..1
    const int wcq  = w & 3;          // 0..3
    const int lr = lane & 15, lk = lane >> 4;

    // XCD-chunked bijective swizzle: 256 wgs, 32/XCD; the 4 cg-blocks of one
    // mgrp are co-XCD (A-tile L2 reuse).
    int wg = (blockIdx.x & 7) * 32 + (blockIdx.x >> 3);
    const int  cg   = wg & 3;        // output group 0..3
    const int  mgrp = wg >> 2;       // 0..63
    const long m0 = (long)mgrp * 1024;   // 4 m-tiles of 256 rows
    const int  n0 = cg * BN;

    const int rl8  = lane >> 3;
    const int scol = (((lane & 7) ^ rl8) << 4);
    const char* baseA = (const char*)xh   + (m0 + w * 8 + rl8) * 1024 + scol;
    const char* baseB = (const char*)Wcat + ((long)(n0 + w * 8 + rl8)) * 1024 + scol;

    // global tile g: mt=g>>3, kt=g&7, LDS parity g&1
#define STAGE_A(g, h) do {                                                   \
        char* _d = lds + ((g) & 1) * 32768 + (h) * 16384 + w * 1024;         \
        const char* _s = baseA + (long)((g) >> 3) * 262144                   \
                         + ((g) & 7) * 128 + (long)(h) * 131072;             \
        __builtin_amdgcn_global_load_lds(GLBP(_s),         LDSP(_d),        16, 0, 0); \
        __builtin_amdgcn_global_load_lds(GLBP(_s + 65536), LDSP(_d + 8192), 16, 0, 0); \
    } while (0)
#define STAGE_B(g, h) do {                                                   \
        char* _d = lds + 65536 + ((g) & 1) * 32768 + (h) * 16384 + w * 1024; \
        const char* _s = baseB + ((g) & 7) * 128 + (long)(h) * 131072;       \
        __builtin_amdgcn_global_load_lds(GLBP(_s),         LDSP(_d),        16, 0, 0); \
        __builtin_amdgcn_global_load_lds(GLBP(_s + 65536), LDSP(_d + 8192), 16, 0, 0); \
    } while (0)

    fx4 acc[2][2][4][2];
    #pragma unroll
    for (int a = 0; a < 2; ++a)
        #pragma unroll
        for (int b = 0; b < 2; ++b)
            #pragma unroll
            for (int c = 0; c < 4; ++c)
                #pragma unroll
                for (int d = 0; d < 2; ++d)
                    acc[a][b][c][d] = (fx4){0.f, 0.f, 0.f, 0.f};

    f16x8 Ar[4][2];    // current A-half fragments [mf][kk]
    f16x8 B0r[2][2];   // B-half0 fragments [nf][kk]
    f16x8 B1r[2][2];   // B-half1 fragments

#define READ_A(c2, h) do {                                                   \
        _Pragma("unroll")                                                    \
        for (int mf = 0; mf < 4; ++mf) {                                     \
            int rl = wrq * 64 + mf * 16 + lr;                                \
            int rb = (c2) * 32768 + (h) * 16384 + rl * 128;                  \
            _Pragma("unroll")                                                \
            for (int kk = 0; kk < 2; ++kk)                                   \
                Ar[mf][kk] = *(const f16x8*)(lds + rb +                      \
                    ((kk * 64 + lk * 16) ^ ((rl & 7) << 4)));                \
        }                                                                    \
    } while (0)
#define READ_B(c2, h, dst) do {                                              \
        _Pragma("unroll")                                                    \
        for (int nf = 0; nf < 2; ++nf) {                                     \
            int rl = wcq * 32 + nf * 16 + lr;                                \
            int rb = 65536 + (c2) * 32768 + (h) * 16384 + rl * 128;          \
            _Pragma("unroll")                                                \
            for (int kk = 0; kk < 2; ++kk)                                   \
                dst[nf][kk] = *(const f16x8*)(lds + rb +                     \
                    ((kk * 64 + lk * 16) ^ ((rl & 7) << 4)));                \
        }                                                                    \
    } while (0)
    // swapped operands: D[col=lane&15 -> m (A)], [reg j -> o (B)]
#define MMACC(Qr, Qc, Br) do {                                               \
        __builtin_amdgcn_s_setprio(1);                                       \
        _Pragma("unroll")                                                    \
        for (int kk = 0; kk < 2; ++kk)                                       \
            _Pragma("unroll")                                                \
            for (int mf = 0; mf < 4; ++mf)                                   \
                _Pragma("unroll")                                            \
                for (int nf = 0; nf < 2; ++nf)                               \
                    acc[Qr][Qc][mf][nf] = __builtin_amdgcn_mfma_f32_16x16x32_f16( \
                        Br[nf][kk], Ar[mf][kk], acc[Qr][Qc][mf][nf], 0, 0, 0);    \
        __builtin_amdgcn_s_setprio(0);                                       \
    } while (0)

    const int g_out = cg;
    _Float16* outp = (g_out == 0) ? xp_h : (g_out == 1) ? f_h : (g_out == 2) ? r_h : cx_h;
    const float* bias = (g_out == 1) ? bfv : (g_out == 2) ? brv : (g_out == 3) ? bcv : nullptr;

    // ---- prologue: tile0 all 4 halves + tile1 A0,B0; land tile0 ----
    STAGE_A(0, 0); STAGE_B(0, 0); STAGE_B(0, 1); STAGE_A(0, 1);
    STAGE_A(1, 0); STAGE_B(1, 0);
    WAITVM(4);
    BAR();

    for (int g = 0; g < NGT; ++g) {
        const int c2 = g & 1;
        // ---- phase 1: Q(0,0) (reads h0 of A and B) ----
        READ_A(c2, 0);
        READ_B(c2, 0, B0r);
        if (g + 1 < NGT) STAGE_B(g + 1, 1);
        WAITLGKM0();
        MMACC(0, 0, B0r);
        // ---- phase 2: Q(0,1) ----
        READ_B(c2, 1, B1r);
        if (g + 1 < NGT) STAGE_A(g + 1, 1);
        WAITLGKM0();
        MMACC(0, 1, B1r);
        // ---- phase 3: Q(1,0) ----
        READ_A(c2, 1);
        BAR();                          // mid: all h0 reads done block-wide
        if (g + 2 < NGT) STAGE_A(g + 2, 0);
        WAITLGKM0();
        MMACC(1, 0, B0r);
        // ---- phase 4: Q(1,1) ----
        if (g + 2 < NGT) STAGE_B(g + 2, 0);
        MMACC(1, 1, B1r);
        if (g < NGT - 2)       WAITVM(4);
        else if (g == NGT - 2) WAITVM(0);
        BAR();                          // tile boundary: tile g+1 landed
        // ---- per-m-tile epilogue (g = mt*8+7): packed f16x4 stores ----
        if ((g & 7) == 7) {
            const long mbase = m0 + (long)(g >> 3) * 256;
            #pragma unroll
            for (int Qr = 0; Qr < 2; ++Qr) {
                #pragma unroll
                for (int Qc = 0; Qc < 2; ++Qc) {
                    #pragma unroll
                    for (int nf = 0; nf < 2; ++nf) {
                        const int ob = Qc * 128 + wcq * 32 + nf * 16 + lk * 4;
                        float4 bv4 = (g_out == 0) ? (float4){0.f, 0.f, 0.f, 0.f}
                                                  : *(const float4*)(bias + ob);
                        #pragma unroll
                        for (int mf = 0; mf < 4; ++mf) {
                            long row = mbase + Qr * 128 + wrq * 64 + mf * 16 + lr;
                            fx4 v = acc[Qr][Qc][mf][nf];
                            f16x4 hv;
                            if (g_out == 1 || g_out == 2) {
                                float p0 = v[0] + bv4.x, p1 = v[1] + bv4.y;
                                float p2 = v[2] + bv4.z, p3 = v[3] + bv4.w;
                                hv[0] = (_Float16)(__builtin_amdgcn_rcpf(1.0f + __expf(-p0)));
                                hv[1] = (_Float16)(__builtin_amdgcn_rcpf(1.0f + __expf(-p1)));
                                hv[2] = (_Float16)(__builtin_amdgcn_rcpf(1.0f + __expf(-p2)));
                                hv[3] = (_Float16)(__builtin_amdgcn_rcpf(1.0f + __expf(-p3)));
                            } else {
                                hv[0] = (_Float16)(v[0] + bv4.x);
                                hv[1] = (_Float16)(v[1] + bv4.y);
                                hv[2] = (_Float16)(v[2] + bv4.z);
                                hv[3] = (_Float16)(v[3] + bv4.w);
                            }
                            *(f16x4*)(outp + row * NOUT + ob) = hv;
                            acc[Qr][Qc][mf][nf] = (fx4){0.f, 0.f, 0.f, 0.f};
                        }
                    }
                }
            }
        }
    }
}

// ---------------- pass 2a: per-chunk affine composition -------------
__global__ __launch_bounds__(256) void chunk_scan_a(
    const _Float16* __restrict__ f_h, const _Float16* __restrict__ xp_h,
    float* __restrict__ chunkA, float* __restrict__ chunkB)
{
    int tid = blockIdx.x * 256 + threadIdx.x;   // 262144
    int chunk = tid >> 13;
    int bo = tid & (BO - 1);
    long base = (long)chunk * CHLEN * BO + bo;
    float a = 1.f, cc = 0.f;
    #pragma unroll 4
    for (int s = 0; s < CHLEN; ++s) {
        long i = base + (long)s * BO;
        float fv = (float)f_h[i];
        float xv = (float)xp_h[i];
        cc = fv * cc + (1.f - fv) * xv;
        a *= fv;
    }
    chunkA[tid] = a;
    chunkB[tid] = cc;
}

// ---------------- pass 2b: propagate chunk states ----
__global__ __launch_bounds__(256) void chunk_prop(
    const float* __restrict__ ct0,
    const float* __restrict__ chunkA, const float* __restrict__ chunkB,
    float* __restrict__ cin, float* __restrict__ c_final)
{
    int bo = blockIdx.x * 256 + threadIdx.x;   // 8192
    float c = ct0[bo];
    #pragma unroll
    for (int ch = 0; ch < NCHUNK; ++ch) {
        cin[ch * BO + bo] = c;
        c = chunkA[ch * BO + bo] * c + chunkB[ch * BO + bo];
    }
    c_final[bo] = c;
}

// ---------------- pass 2c: final scan producing ht -------------------
__global__ __launch_bounds__(256) void chunk_scan_h(
    const _Float16* __restrict__ xp_h, const _Float16* __restrict__ f_h,
    const _Float16* __restrict__ r_h,  const _Float16* __restrict__ cx_h,
    const float* __restrict__ cin, float* __restrict__ ht)
{
    int tid = blockIdx.x * 256 + threadIdx.x;   // 262144
    int chunk = tid >> 13;
    int bo = tid & (BO - 1);
    long base = (long)chunk * CHLEN * BO + bo;
    float c = cin[tid];
    #pragma unroll 4
    for (int s = 0; s < CHLEN; ++s) {
        long i = base + (long)s * BO;
        float fv = (float)f_h[i];
        float xv = (float)xp_h[i];
        float rv = (float)r_h[i];
        float cxv = (float)cx_h[i];
        c = fv * c + (1.f - fv) * xv;
        float e = __expf(2.f * c);                       // tanh = (e-1)/(e+1)
        float th = (e - 1.f) * __builtin_amdgcn_rcpf(e + 1.f);
        ht[i] = rv * th + (1.f - rv) * cxv;
    }
}

// ---------------- launcher ----------------
extern "C" void kernel_launch(void* const* d_in, const int* in_sizes, int n_in,
                              void* d_out, int out_size, void* d_ws, size_t ws_size,
                              hipStream_t stream) {
    const float* xt  = (const float*)d_in[0];
    const float* ct0 = (const float*)d_in[1];
    const float* Wx  = (const float*)d_in[2];
    const float* Wf  = (const float*)d_in[3];
    const float* bf_ = (const float*)d_in[4];
    const float* Wr  = (const float*)d_in[5];
    const float* br_ = (const float*)d_in[6];
    const float* Wc  = (const float*)d_in[7];
    const float* bc_ = (const float*)d_in[8];

    float* ht      = (float*)d_out;
    float* c_final = ht + (size_t)MROWS * NOUT;

    char* ws = (char*)d_ws;
    _Float16* Wcat = (_Float16*)ws;                          // 1 MiB
    _Float16* xh   = (_Float16*)(ws + (1 << 20));            // 64 MiB
    _Float16* xp_h = xh + (size_t)MROWS * NIN;               // 32 MiB each
    _Float16* f_h  = xp_h + (size_t)MROWS * NOUT;
    _Float16* r_h  = f_h  + (size_t)MROWS * NOUT;
    _Float16* cx_h = r_h  + (size_t)MROWS * NOUT;
    float* chunkA  = (float*)(cx_h + (size_t)MROWS * NOUT);  // 1 MiB
    float* chunkB  = chunkA + NCHUNK * BO;
    float* cin     = chunkB + NCHUNK * BO;

    convert_w<<<512, 256, 0, stream>>>(Wx, Wf, Wr, Wc, Wcat);
    convert_x<<<(MROWS * NIN / 8) / 256, 256, 0, stream>>>(xt, xh);
    gemm_proj<<<256, 512, 0, stream>>>(
        xh, Wcat, bf_, br_, bc_, xp_h, f_h, r_h, cx_h);
    chunk_scan_a<<<(NCHUNK * BO) / 256, 256, 0, stream>>>(f_h, xp_h, chunkA, chunkB);
    chunk_prop<<<BO / 256, 256, 0, stream>>>(ct0, chunkA, chunkB, cin, c_final);
    chunk_scan_h<<<(NCHUNK * BO) / 256, 256, 0, stream>>>(xp_h, f_h, r_h, cx_h, cin, ht);
}